// Round 1
// baseline (63.627 us; speedup 1.0000x reference)
//
#include <hip/hip_runtime.h>
#include <stdint.h>

#define MM 8
#define KK 8192
#define NN 8192
#define KC 256            // k-chunk per block in the main kernel
#define FP8MAXV 448.0f

// ---------------------------------------------------------------------------
// Bit-exact round-to-nearest-even f32 -> fp8 e4m3fn -> f32 (|v| <= ~448).
// Normal range (|v| >= 2^-6): keep 1+3 mantissa bits via add-half-and-truncate.
// Subnormal range (|v| < 2^-6): quantum is 2^-9; rintf is RNE on AMD (v_rndne).
// ---------------------------------------------------------------------------
__device__ __forceinline__ float fp8_e4m3_round(float v) {
    uint32_t u = __float_as_uint(v);
    uint32_t mag = u & 0x7fffffffu;
    if (mag >= 0x3C800000u) {            // |v| >= 2^-6 : normal e4m3
        uint32_t lsb = (u >> 20) & 1u;   // RNE: add (half - 1) + lsb
        uint32_t r = u + 0x0007FFFFu + lsb;
        r &= 0xFFF00000u;                // keep sign + exp + 3 mantissa bits
        return __uint_as_float(r);
    }
    return rintf(v * 512.0f) * (1.0f / 512.0f);
}

// ---------------------------------------------------------------------------
// Kernel 1: per-row amax -> scale; quantize x; store transposed xqT[k][m] in ws.
// ws layout (floats): [0..7] = x_scale_inv per row; [64 ..] = xqT (KK*MM floats)
// ---------------------------------------------------------------------------
__global__ __launch_bounds__(256) void prep_kernel(const float* __restrict__ x,
                                                   float* __restrict__ ws) {
    const int m = blockIdx.x;
    const int tid = threadIdx.x;
    const float* row = x + (size_t)m * KK;

    float amax = 0.0f;
    for (int k = tid * 4; k < KK; k += 256 * 4) {
        float4 v = *(const float4*)(row + k);
        amax = fmaxf(amax, fmaxf(fmaxf(fabsf(v.x), fabsf(v.y)),
                                 fmaxf(fabsf(v.z), fabsf(v.w))));
    }
#pragma unroll
    for (int off = 32; off >= 1; off >>= 1)
        amax = fmaxf(amax, __shfl_xor(amax, off, 64));

    __shared__ float sred[4];
    __shared__ float sscale;
    if ((tid & 63) == 0) sred[tid >> 6] = amax;
    __syncthreads();
    if (tid == 0) {
        float a = fmaxf(fmaxf(sred[0], sred[1]), fmaxf(sred[2], sred[3]));
        float scale = (a > 0.0f) ? (FP8MAXV / a) : 1.0f;
        sscale = scale;
        ws[m] = 1.0f / scale;            // matches reference's 1.0/x_scale
    }
    __syncthreads();
    const float scale = sscale;

    float* xqT = ws + 64;
    for (int k = tid; k < KK; k += 256)
        xqT[(size_t)k * MM + m] = fp8_e4m3_round(row[k] * scale);
}

// ---------------------------------------------------------------------------
// Kernel 2: out[m][n] = bias[n]  (re-done every call so replays are correct)
// ---------------------------------------------------------------------------
__global__ __launch_bounds__(256) void init_kernel(const float* __restrict__ bias,
                                                   float* __restrict__ out) {
    int idx = blockIdx.x * 256 + threadIdx.x;   // grid covers MM*NN exactly
    out[idx] = bias[idx & (NN - 1)];
}

// ---------------------------------------------------------------------------
// Kernel 3: split-K GEMV. Block = 256 threads, one output column per thread.
// grid.x = NN/256 column tiles, grid.y = KK/KC k-chunks.
// Each thread streams KC rows of W down its column (coalesced across the wave),
// multiplies by the block-uniform quantized activations held in LDS, and
// atomically accumulates the scaled partials into out (bias pre-initialized).
// ---------------------------------------------------------------------------
__global__ __launch_bounds__(256) void gemm_kernel(const float* __restrict__ W,
                                                   const float* __restrict__ wsinv,
                                                   const float* __restrict__ ws,
                                                   float* __restrict__ out) {
    const int n  = blockIdx.x * 256 + threadIdx.x;
    const int k0 = blockIdx.y * KC;

    __shared__ float sxq[KC * MM];               // 8 KB
    {
        const float4* src = (const float4*)(ws + 64 + (size_t)k0 * MM);
        float4* dst = (float4*)sxq;
#pragma unroll
        for (int i = 0; i < (KC * MM) / 4 / 256; ++i)
            dst[threadIdx.x + i * 256] = src[threadIdx.x + i * 256];
    }
    __syncthreads();

    float acc[MM];
#pragma unroll
    for (int m = 0; m < MM; ++m) acc[m] = 0.0f;

    const float* Wp = W + (size_t)k0 * NN + n;
#pragma unroll 8
    for (int k = 0; k < KC; ++k) {
        float w = Wp[(size_t)k * NN];
        const float4* a4 = (const float4*)(sxq + k * MM);
        float4 a0 = a4[0];
        float4 a1 = a4[1];
        acc[0] = fmaf(a0.x, w, acc[0]);
        acc[1] = fmaf(a0.y, w, acc[1]);
        acc[2] = fmaf(a0.z, w, acc[2]);
        acc[3] = fmaf(a0.w, w, acc[3]);
        acc[4] = fmaf(a1.x, w, acc[4]);
        acc[5] = fmaf(a1.y, w, acc[5]);
        acc[6] = fmaf(a1.z, w, acc[6]);
        acc[7] = fmaf(a1.w, w, acc[7]);
    }

    const float wsn = wsinv[n];
#pragma unroll
    for (int m = 0; m < MM; ++m)
        unsafeAtomicAdd(out + (size_t)m * NN + n, acc[m] * ws[m] * wsn);
}

extern "C" void kernel_launch(void* const* d_in, const int* in_sizes, int n_in,
                              void* d_out, int out_size, void* d_ws, size_t ws_size,
                              hipStream_t stream) {
    const float* x     = (const float*)d_in[0];   // [M,K] f32
    const float* W     = (const float*)d_in[1];   // [K,N] f32 (fp8 values)
    const float* wsinv = (const float*)d_in[2];   // [N]   f32
    const float* bias  = (const float*)d_in[3];   // [N]   f32
    float* out = (float*)d_out;                   // [M,N] f32
    float* ws  = (float*)d_ws;                    // scales + xqT (~257 KB)

    prep_kernel<<<MM, 256, 0, stream>>>(x, ws);
    init_kernel<<<(MM * NN) / 256, 256, 0, stream>>>(bias, out);
    gemm_kernel<<<dim3(NN / 256, KK / KC), 256, 0, stream>>>(W, wsinv, ws, out);
}